// Round 1
// baseline (39616.077 us; speedup 1.0000x reference)
//
#include <hip/hip_runtime.h>

// ---------------------------------------------------------------------------
// BiLSTM encoder, persistent-kernel implementation (Round 1: correctness-first)
// B=32, T=1024, D=H=512, L=2, bidirectional, length-masked.
//
// Grid: 256 blocks x 256 threads, 1 block/CU (LDS-limited), 4 groups of 64:
//   group 0: fwd layer0 | group 1: fwd layer1 | group 2: bwd layer0 | group 3: bwd layer1
// Each block owns 8 hidden units (x4 gates = 32 z-columns) and keeps its
// fp32 weight slice (1024x32 = 128 KiB) in LDS for the whole sweep.
// Layer 1 trails layer 0 by one barrier step (y0 passed via 2-slot ring).
// Custom agent-scope atomic barrier per direction (128 blocks each).
// ---------------------------------------------------------------------------

#define B_ 32
#define T_ 1024
#define D_ 512
#define H_ 512
#define K_ 1024          // D + H
#define NC_ 32           // z-columns per block (8 j x 4 gates)
#define JB_ 8            // hidden units per block
#define CK_ 128          // k-chunk staged in LDS
#define NCH_ 8           // chunks per step (K_/CK_)
#define INROW_ 132       // CK_ + 4 pad (bank-conflict)
#define ZROW_ 33         // 32 + 1 pad

static constexpr int    kSmemFloats = K_ * NC_ + B_ * INROW_ + 32 * ZROW_ + 32;
static constexpr size_t kSmemBytes  = (size_t)kSmemFloats * sizeof(float); // ~148.8 KiB

// ws layout (floats): [0..256) barrier words | h[4][2][B][H] | c[4][B][H] | ring[2][2][B][H]
static constexpr int    kHOff  = 256;
static constexpr int    kHSize = 4 * 2 * B_ * H_;
static constexpr int    kCOff  = kHOff + kHSize;
static constexpr int    kCSize = 4 * B_ * H_;
static constexpr int    kROff  = kCOff + kCSize;
static constexpr int    kRSize = 2 * 2 * B_ * H_;
static constexpr size_t kWsBytes = (size_t)(kROff + kRSize) * sizeof(float); // ~1.05 MB

__device__ __forceinline__ float sigm(float x) { return 1.0f / (1.0f + __expf(-x)); }

// Two-counter sense barrier, agent scope. Data release via __threadfence().
__device__ __forceinline__ void gbarrier(unsigned* cnt, unsigned* gen, unsigned nb) {
  __syncthreads();
  if (threadIdx.x == 0) {
    __threadfence();  // release: make this block's stores visible device-wide
    unsigned g = __hip_atomic_load(gen, __ATOMIC_RELAXED, __HIP_MEMORY_SCOPE_AGENT);
    unsigned prev = __hip_atomic_fetch_add(cnt, 1u, __ATOMIC_ACQ_REL, __HIP_MEMORY_SCOPE_AGENT);
    if (prev == nb - 1u) {
      __hip_atomic_store(cnt, 0u, __ATOMIC_RELAXED, __HIP_MEMORY_SCOPE_AGENT);
      __hip_atomic_fetch_add(gen, 1u, __ATOMIC_ACQ_REL, __HIP_MEMORY_SCOPE_AGENT);
    } else {
      unsigned cur;
      do {
        __builtin_amdgcn_s_sleep(1);
        cur = __hip_atomic_load(gen, __ATOMIC_RELAXED, __HIP_MEMORY_SCOPE_AGENT);
      } while (cur == g);
    }
    __threadfence();  // acquire: invalidate stale cached data before next step
  }
  __syncthreads();
}

__global__ __launch_bounds__(256, 1)
void bilstm_persistent(const float* __restrict__ inp, const int* __restrict__ lens,
                       const float* __restrict__ Wf, const float* __restrict__ bf,
                       const float* __restrict__ Wb, const float* __restrict__ bbias,
                       float* __restrict__ out, float* __restrict__ ws) {
  extern __shared__ float smem[];
  float* wlds  = smem;                    // [K_][NC_]
  float* inlds = smem + K_ * NC_;         // [B_][INROW_]
  float* zlds  = inlds + B_ * INROW_;     // [NC_][ZROW_]
  float* blds  = zlds + 32 * ZROW_;       // [NC_]

  const int tid    = threadIdx.x;
  const int blk    = blockIdx.x;
  const int group  = blk >> 6;     // 0..3
  const int gslice = blk & 63;
  const int j0     = gslice * JB_;
  const int dir    = group >> 1;   // 0 fwd, 1 bwd
  const int layer  = group & 1;

  unsigned* bar = (unsigned*)ws;
  float* hws  = ws + kHOff;
  float* cws  = ws + kCOff;
  float* ring = ws + kROff;

  const float* Wg = (dir == 0 ? Wf : Wb) + (size_t)layer * K_ * 2048;
  const float* bg = (dir == 0 ? bf : bbias) + layer * 2048;

  // --- stage weight slice into LDS (once): wlds[k][c], c = gate*8 + jj ---
  for (int kb = 0; kb < K_; kb += 8) {
    int k = kb + (tid >> 5);
    int c = tid & 31;
    wlds[k * NC_ + c] = Wg[(size_t)k * 2048 + (c >> 3) * 512 + j0 + (c & 7)];
  }
  if (tid < 32) blds[tid] = bg[(tid >> 3) * 512 + j0 + (tid & 7)];
  __syncthreads();

  const int tc = tid & 15, tb = tid >> 4;  // GEMM phase: b-pair {tb,tb+16}, cols {2tc,2tc+1}
  const int bi = tid >> 3;                 // staging + pointwise batch index
  const int ks = (tid & 7) * 16;           // staging k offset within chunk
  const int jj = tid & 7;                  // pointwise hidden offset
  const int mylen = lens[bi];

  float* hg    = hws + group * (2 * B_ * H_);
  float* cg    = cws + group * (B_ * H_);
  float* ringd = ring + dir * (2 * B_ * H_);
  const int hidx = bi * H_ + j0 + jj;

  for (int s = 0; s <= T_; ++s) {
    const bool active = (layer == 0) ? (s < T_) : (s >= 1);
    if (active) {
      const int t = (layer == 0) ? s : (s - 1);
      const float* hbuf_rd = hg + (s & 1) * (B_ * H_);
      const float* xrow;
      if (layer == 0) {
        int tr = t;
        if (dir == 1) tr = (t < mylen) ? (mylen - 1 - t) : t;  // reversed sequence
        xrow = inp + ((size_t)bi * T_ + tr) * D_;
      } else {
        xrow = ringd + (t & 1) * (B_ * H_) + bi * H_;          // y0[t] from ring
      }
      const float* hrow = hbuf_rd + bi * H_;

      float acc00 = 0.f, acc01 = 0.f, acc10 = 0.f, acc11 = 0.f;

      // prefetch chunk 0 (always x-part)
      float4 p0, p1, p2, p3;
      {
        const float* src = xrow + ks;
        p0 = *(const float4*)(src);     p1 = *(const float4*)(src + 4);
        p2 = *(const float4*)(src + 8); p3 = *(const float4*)(src + 12);
      }

      for (int kc = 0; kc < NCH_; ++kc) {
        __syncthreads();  // previous chunk fully consumed
        float* dst = inlds + bi * INROW_ + ks;
        *(float4*)(dst)      = p0; *(float4*)(dst + 4)  = p1;
        *(float4*)(dst + 8)  = p2; *(float4*)(dst + 12) = p3;
        __syncthreads();  // staged chunk visible
        if (kc + 1 < NCH_) {  // prefetch next chunk while FMAs run
          int k0n = (kc + 1) * CK_;
          const float* src = ((k0n < D_) ? (xrow + k0n) : (hrow + (k0n - D_))) + ks;
          p0 = *(const float4*)(src);     p1 = *(const float4*)(src + 4);
          p2 = *(const float4*)(src + 8); p3 = *(const float4*)(src + 12);
        }
        const float* ap0 = inlds + tb * INROW_;
        const float* ap1 = ap0 + 16 * INROW_;
        const float* wp  = wlds + (kc * CK_) * NC_ + 2 * tc;
#pragma unroll
        for (int k4 = 0; k4 < CK_; k4 += 4) {
          float4 a0 = *(const float4*)(ap0 + k4);
          float4 a1 = *(const float4*)(ap1 + k4);
          float2 w0 = *(const float2*)(wp + (k4 + 0) * NC_);
          float2 w1 = *(const float2*)(wp + (k4 + 1) * NC_);
          float2 w2 = *(const float2*)(wp + (k4 + 2) * NC_);
          float2 w3 = *(const float2*)(wp + (k4 + 3) * NC_);
          acc00 = fmaf(a0.x, w0.x, acc00); acc01 = fmaf(a0.x, w0.y, acc01);
          acc10 = fmaf(a1.x, w0.x, acc10); acc11 = fmaf(a1.x, w0.y, acc11);
          acc00 = fmaf(a0.y, w1.x, acc00); acc01 = fmaf(a0.y, w1.y, acc01);
          acc10 = fmaf(a1.y, w1.x, acc10); acc11 = fmaf(a1.y, w1.y, acc11);
          acc00 = fmaf(a0.z, w2.x, acc00); acc01 = fmaf(a0.z, w2.y, acc01);
          acc10 = fmaf(a1.z, w2.x, acc10); acc11 = fmaf(a1.z, w2.y, acc11);
          acc00 = fmaf(a0.w, w3.x, acc00); acc01 = fmaf(a0.w, w3.y, acc01);
          acc10 = fmaf(a1.w, w3.x, acc10); acc11 = fmaf(a1.w, w3.y, acc11);
        }
      }

      // exchange z through LDS so each pointwise thread sees all 4 gates
      zlds[(2 * tc) * ZROW_ + tb]          = acc00;
      zlds[(2 * tc + 1) * ZROW_ + tb]      = acc01;
      zlds[(2 * tc) * ZROW_ + tb + 16]     = acc10;
      zlds[(2 * tc + 1) * ZROW_ + tb + 16] = acc11;
      __syncthreads();

      // pointwise LSTM cell update: thread -> (b = bi, hidden j0+jj)
      float zi = zlds[(0 + jj) * ZROW_ + bi]  + blds[0 + jj];
      float zj = zlds[(8 + jj) * ZROW_ + bi]  + blds[8 + jj];
      float zf = zlds[(16 + jj) * ZROW_ + bi] + blds[16 + jj];
      float zo = zlds[(24 + jj) * ZROW_ + bi] + blds[24 + jj];
      float co = cg[hidx];
      float ig = sigm(zi), fg = sigm(zf + 1.0f), og = sigm(zo);
      float cn = fg * co + ig * tanhf(zj);
      float hn = og * tanhf(cn);
      bool  m  = (t < mylen);
      float hold = hbuf_rd[hidx];
      cg[hidx] = m ? cn : co;
      hg[((s + 1) & 1) * (B_ * H_) + hidx] = m ? hn : hold;  // write buffer for step s+1
      float y = m ? hn : 0.0f;
      if (layer == 0) {
        ringd[(t & 1) * (B_ * H_) + hidx] = y;
      } else {
        int ot = t;
        if (dir == 1) ot = (t < mylen) ? (mylen - 1 - t) : t;  // un-reverse on store
        out[((size_t)bi * T_ + ot) * 1024 + dir * 512 + j0 + jj] = y;
      }
    }
    gbarrier(bar + dir * 64, bar + dir * 64 + 32, 128u);
  }
}

extern "C" void kernel_launch(void* const* d_in, const int* in_sizes, int n_in,
                              void* d_out, int out_size, void* d_ws, size_t ws_size,
                              hipStream_t stream) {
  const float* inp   = (const float*)d_in[0];
  const int*   lens  = (const int*)d_in[1];
  const float* Wf    = (const float*)d_in[2];
  const float* bf    = (const float*)d_in[3];
  const float* Wb    = (const float*)d_in[4];
  const float* bbias = (const float*)d_in[5];
  float*       out   = (float*)d_out;
  float*       ws    = (float*)d_ws;

  (void)in_sizes; (void)n_in; (void)out_size; (void)ws_size;

  // zero h/c states, ring, and barrier counters (deterministic per call)
  hipMemsetAsync(d_ws, 0, kWsBytes, stream);

  hipFuncSetAttribute((const void*)bilstm_persistent,
                      hipFuncAttributeMaxDynamicSharedMemorySize, (int)kSmemBytes);

  bilstm_persistent<<<dim3(256), dim3(256), kSmemBytes, stream>>>(
      inp, lens, Wf, bf, Wb, bbias, out, ws);
}

// Round 2
// 22025.078 us; speedup vs baseline: 1.7987x; 1.7987x over previous
//
#include <hip/hip_runtime.h>
#include <stdint.h>

// ---------------------------------------------------------------------------
// BiLSTM encoder, persistent MFMA kernel (Round 2).
// 256 blocks x 256 threads, 1 block/CU. 4 groups of 64 blocks:
//   g0 fwd-L0 | g1 fwd-L1 | g2 bwd-L0 | g3 bwd-L1   (L1 trails L0 by 1 step)
// Per block: 32 z-columns (8 hidden units x 4 gates, col = jj*4+gate).
// GEMM: split-bf16 (hi/lo) 3-product MFMA 16x16x32 -> fp32-grade accuracy.
// Weights in LDS as bf16 hi/lo [col][k], XOR-swizzled. A staged per 128-k
// chunk (hi/lo), 2-deep register prefetch. h/ring in ws as packed hi|lo u32.
// Flag-based (no-RMW) grid barrier per direction.
// ---------------------------------------------------------------------------

#define B_ 32
#define T_ 1024
#define D_ 512
#define H_ 512
#define K_ 1024
#define CK_ 128
#define NCH_ 8

typedef __attribute__((ext_vector_type(8))) short bf16x8;
typedef __attribute__((ext_vector_type(4))) float f32x4;
typedef __attribute__((ext_vector_type(4))) unsigned int u32x4;

// LDS byte layout
#define WHI_OFF   0          // [32 cols][1024 k] ushort, pitch 2048B, swz ((c&7)<<4)
#define WLO_OFF   65536
#define AHI_OFF   131072     // [32 rows][128 k] ushort, pitch 256B, swz ((r&7)<<4)
#define ALO_OFF   139264
#define LDS_BYTES 147456
// z-exchange (float[32][33], 4224B) reuses the AHI region between steps.

// ws layout (u32 units)
#define FLAGS_OFF 0                            // [2 dirs][128] step flags
#define H_OFF     256                          // [4 grp][2 buf][B][H] packed u32
#define C_OFF     (H_OFF + 4*2*B_*H_)          // [4 grp][B][H] fp32
#define R_OFF     (C_OFF + 4*B_*H_)            // [2 dir][2 slot][B][H] packed u32
static constexpr size_t kWsU32  = R_OFF + 2*2*B_*H_;
static constexpr size_t kWsBytes = kWsU32 * 4;   // ~1.05 MB

__device__ __forceinline__ unsigned short bf16_rtn(float f) {
  unsigned u = __builtin_bit_cast(unsigned, f);
  unsigned r = u + 0x7FFFu + ((u >> 16) & 1u);
  return (unsigned short)(r >> 16);
}
__device__ __forceinline__ float bf16_to_f(unsigned short h) {
  return __builtin_bit_cast(float, (unsigned)h << 16);
}
__device__ __forceinline__ void split_f32(float f, unsigned short& hi, unsigned short& lo) {
  hi = bf16_rtn(f);
  lo = bf16_rtn(f - bf16_to_f(hi));
}
__device__ __forceinline__ unsigned pack_f32(float f) {
  unsigned short hi, lo; split_f32(f, hi, lo);
  return ((unsigned)hi << 16) | (unsigned)lo;
}

struct PF { u32x4 v[4]; };   // one staged 16-element slice (64B) per thread

__global__ __launch_bounds__(256, 1)
void bilstm_mfma(const float* __restrict__ inp, const int* __restrict__ lens,
                 const float* __restrict__ Wf, const float* __restrict__ bfp,
                 const float* __restrict__ Wb, const float* __restrict__ bbp,
                 float* __restrict__ out, unsigned* __restrict__ ws) {
  extern __shared__ char lds[];
  const int tid    = threadIdx.x;
  const int blk    = blockIdx.x;
  const int group  = blk >> 6;
  const int gslice = blk & 63;
  const int j0     = gslice * 8;
  const int dir    = group >> 1;
  const int layer  = group & 1;
  const int hBH    = B_ * H_;

  unsigned* flags = ws + FLAGS_OFF + dir * 128;
  unsigned* hg    = ws + H_OFF + group * (2 * hBH);
  float*    cg    = (float*)(ws + C_OFF) + group * hBH;
  unsigned* ringd = ws + R_OFF + dir * (2 * hBH);

  const float* Wg = (dir == 0 ? Wf : Wb) + (size_t)layer * K_ * 2048;
  const float* bg = (dir == 0 ? bfp : bbp) + layer * 2048;

  // ---- stage weights into LDS as bf16 hi/lo, col-major, XOR-swizzled ----
  for (int it = 0; it < 16; ++it) {
    int tt = tid + 256 * it;           // 4096 tasks = 1024 k x 4 gates
    int k = tt >> 2, gate = tt & 3;
    const float* src = Wg + (size_t)k * 2048 + gate * 512 + j0;
    float4 w0 = *(const float4*)src;
    float4 w1 = *(const float4*)(src + 4);
    float wv[8] = {w0.x, w0.y, w0.z, w0.w, w1.x, w1.y, w1.z, w1.w};
#pragma unroll
    for (int u = 0; u < 8; ++u) {
      int c = u * 4 + gate;            // col = jj*4 + gate
      unsigned short hi, lo; split_f32(wv[u], hi, lo);
      int byte = (c * 2048 + k * 2) ^ ((c & 7) << 4);
      *(unsigned short*)(lds + WHI_OFF + byte) = hi;
      *(unsigned short*)(lds + WLO_OFF + byte) = lo;
    }
  }

  const int bi = tid >> 3;             // batch row (staging + pointwise)
  const int jj = tid & 7;              // hidden offset (pointwise)
  const int q  = tid & 7;              // k-segment (staging)
  const int mylen = lens[bi];
  const float bias_i = bg[0 * 512 + j0 + jj];
  const float bias_j = bg[1 * 512 + j0 + jj];
  const float bias_f = bg[2 * 512 + j0 + jj];
  const float bias_o = bg[3 * 512 + j0 + jj];

  const int lane = tid & 63, wvid = tid >> 6;
  const int mi = wvid >> 1, ni = wvid & 1;
  const int fr = lane & 15, fq = lane >> 4;
  const int arow = mi * 16 + fr;
  const int bcol = ni * 16 + fr;
  const int swzA = (arow & 7) << 4;
  const int swzB = (bcol & 7) << 4;
  const char* Abh = lds + AHI_OFF + arow * 256;
  const char* Abl = lds + ALO_OFF + arow * 256;
  const char* Wbh = lds + WHI_OFF + bcol * 2048;
  const char* Wbl = lds + WLO_OFF + bcol * 2048;
  float* zb = (float*)(lds + AHI_OFF);
  const int hidx = bi * H_ + j0 + jj;

  __syncthreads();  // weights staged

  for (int s = 0; s <= T_; ++s) {
    const bool active = (layer == 0) ? (s < T_) : (s >= 1);
    if (active) {
      const int t = (layer == 0) ? s : (s - 1);
      const unsigned* hrd = hg + (s & 1) * hBH;
      const float*    xrow  = nullptr;
      const unsigned* prow0 = nullptr;
      if (layer == 0) {
        int tr = t;
        if (dir == 1) tr = (t < mylen) ? (mylen - 1 - t) : t;
        xrow = inp + ((size_t)bi * T_ + tr) * D_;
      } else {
        prow0 = ringd + (t & 1) * hBH + bi * H_;
      }
      const unsigned* prowh = hrd + bi * H_;

      auto prefetch = [&](int kc) -> PF {
        PF r;
        int k0 = kc * CK_ + q * 16;
        if (layer == 0 && k0 < 512) {
          const float* sp = xrow + k0;
          r.v[0] = *(const u32x4*)(sp + 0);  r.v[1] = *(const u32x4*)(sp + 4);
          r.v[2] = *(const u32x4*)(sp + 8);  r.v[3] = *(const u32x4*)(sp + 12);
        } else {
          const unsigned* sp = (k0 < 512) ? (prow0 + k0) : (prowh + (k0 - 512));
          r.v[0] = *(const u32x4*)(sp + 0);  r.v[1] = *(const u32x4*)(sp + 4);
          r.v[2] = *(const u32x4*)(sp + 8);  r.v[3] = *(const u32x4*)(sp + 12);
        }
        return r;
      };

      auto stage_write = [&](const PF& p, bool isf32) {
        unsigned hp[8], lp[8];
        const unsigned* pe = (const unsigned*)&p;
        if (isf32) {
#pragma unroll
          for (int e = 0; e < 8; ++e) {
            float f0 = __builtin_bit_cast(float, pe[2 * e]);
            float f1 = __builtin_bit_cast(float, pe[2 * e + 1]);
            unsigned short h0, l0, h1, l1;
            split_f32(f0, h0, l0); split_f32(f1, h1, l1);
            hp[e] = (unsigned)h0 | ((unsigned)h1 << 16);
            lp[e] = (unsigned)l0 | ((unsigned)l1 << 16);
          }
        } else {
#pragma unroll
          for (int e = 0; e < 8; ++e) {
            unsigned p0 = pe[2 * e], p1 = pe[2 * e + 1];
            hp[e] = (p0 >> 16) | (p1 & 0xFFFF0000u);
            lp[e] = (p0 & 0xFFFFu) | (p1 << 16);
          }
        }
        int b0 = (bi * 256 + q * 32) ^ ((bi & 7) << 4);
        u32x4 hA = {hp[0], hp[1], hp[2], hp[3]}, hB = {hp[4], hp[5], hp[6], hp[7]};
        u32x4 lA = {lp[0], lp[1], lp[2], lp[3]}, lB = {lp[4], lp[5], lp[6], lp[7]};
        *(u32x4*)(lds + AHI_OFF + b0)        = hA;
        *(u32x4*)(lds + AHI_OFF + (b0 ^ 16)) = hB;
        *(u32x4*)(lds + ALO_OFF + b0)        = lA;
        *(u32x4*)(lds + ALO_OFF + (b0 ^ 16)) = lB;
      };

      f32x4 acc0 = {0, 0, 0, 0}, acc1 = {0, 0, 0, 0}, acc2 = {0, 0, 0, 0};
      PF pfa = prefetch(0);
      PF pfb = prefetch(1);
#pragma unroll
      for (int kc = 0; kc < NCH_; ++kc) {
        __syncthreads();                     // prev chunk fully consumed
        stage_write((kc & 1) ? pfb : pfa, layer == 0 && kc < 4);
        __syncthreads();                     // chunk visible
        if (kc + 2 < NCH_) {                 // 2-deep prefetch
          if (kc & 1) pfb = prefetch(kc + 2); else pfa = prefetch(kc + 2);
        }
        const char* wh = Wbh + kc * 256;
        const char* wl = Wbl + kc * 256;
#pragma unroll
        for (int kk = 0; kk < 4; ++kk) {
          int ao = (kk * 64 + fq * 16) ^ swzA;
          int bo = (kk * 64 + fq * 16) ^ swzB;
          bf16x8 ah = *(const bf16x8*)(Abh + ao);
          bf16x8 al = *(const bf16x8*)(Abl + ao);
          bf16x8 bh = *(const bf16x8*)(wh + bo);
          bf16x8 bl = *(const bf16x8*)(wl + bo);
          acc0 = __builtin_amdgcn_mfma_f32_16x16x32_bf16(ah, bh, acc0, 0, 0, 0);
          acc1 = __builtin_amdgcn_mfma_f32_16x16x32_bf16(ah, bl, acc1, 0, 0, 0);
          acc2 = __builtin_amdgcn_mfma_f32_16x16x32_bf16(al, bh, acc2, 0, 0, 0);
        }
      }

      __syncthreads();   // all waves done reading chunk LDS
      {
        int col = ni * 16 + fr;
        int row0 = mi * 16 + fq * 4;
#pragma unroll
        for (int r = 0; r < 4; ++r)
          zb[col * 33 + row0 + r] = acc0[r] + acc1[r] + acc2[r];
      }
      __syncthreads();

      // pointwise LSTM cell: thread -> (batch bi, hidden j0+jj)
      float zi = zb[(jj * 4 + 0) * 33 + bi] + bias_i;
      float zj = zb[(jj * 4 + 1) * 33 + bi] + bias_j;
      float zf = zb[(jj * 4 + 2) * 33 + bi] + bias_f;
      float zo = zb[(jj * 4 + 3) * 33 + bi] + bias_o;
      float co = cg[hidx];
      float ig = 1.f / (1.f + __expf(-zi));
      float fg = 1.f / (1.f + __expf(-(zf + 1.0f)));
      float og = 1.f / (1.f + __expf(-zo));
      float cn = fg * co + ig * tanhf(zj);
      float hn = og * tanhf(cn);
      bool  m  = (t < mylen);
      unsigned holdp = hrd[hidx];
      cg[hidx] = m ? cn : co;
      unsigned hnp = pack_f32(hn);
      hg[((s + 1) & 1) * hBH + hidx] = m ? hnp : holdp;
      if (layer == 0) {
        ringd[(t & 1) * hBH + hidx] = m ? hnp : 0u;
      } else {
        int ot = t;
        if (dir == 1) ot = (t < mylen) ? (mylen - 1 - t) : t;
        out[((size_t)bi * T_ + ot) * 1024 + dir * 512 + j0 + jj] = m ? hn : 0.0f;
      }
    }

    if (s < T_) {   // flag barrier over this direction's 128 blocks
      __syncthreads();
      if (tid == 0) {
        __threadfence();
        __hip_atomic_store(&flags[layer * 64 + gslice], (unsigned)(s + 1),
                           __ATOMIC_RELAXED, __HIP_MEMORY_SCOPE_AGENT);
      }
      if (tid < 64) {
        unsigned target = (unsigned)(s + 1);
        while (true) {
          unsigned a = __hip_atomic_load(&flags[tid], __ATOMIC_RELAXED,
                                         __HIP_MEMORY_SCOPE_AGENT);
          unsigned b = __hip_atomic_load(&flags[tid + 64], __ATOMIC_RELAXED,
                                         __HIP_MEMORY_SCOPE_AGENT);
          bool ok = (a >= target) && (b >= target);
          if (__all(ok)) break;
          __builtin_amdgcn_s_sleep(1);
        }
        if (tid == 0) __threadfence();
      }
      __syncthreads();
    }
  }
}

extern "C" void kernel_launch(void* const* d_in, const int* in_sizes, int n_in,
                              void* d_out, int out_size, void* d_ws, size_t ws_size,
                              hipStream_t stream) {
  const float* inp   = (const float*)d_in[0];
  const int*   lensp = (const int*)d_in[1];
  const float* Wf    = (const float*)d_in[2];
  const float* bfp   = (const float*)d_in[3];
  const float* Wb    = (const float*)d_in[4];
  const float* bbp   = (const float*)d_in[5];
  float*       outp  = (float*)d_out;
  unsigned*    wsp   = (unsigned*)d_ws;
  (void)in_sizes; (void)n_in; (void)out_size; (void)ws_size;

  hipMemsetAsync(d_ws, 0, kWsBytes, stream);
  hipFuncSetAttribute((const void*)bilstm_mfma,
                      hipFuncAttributeMaxDynamicSharedMemorySize, LDS_BYTES);
  bilstm_mfma<<<dim3(256), dim3(256), LDS_BYTES, stream>>>(
      inp, lensp, Wf, bfp, Wb, bbp, outp, wsp);
}